// Round 10
// baseline (44647.897 us; speedup 1.0000x reference)
//
#include <hip/hip_runtime.h>

typedef unsigned short u16;
typedef __attribute__((ext_vector_type(8))) short short8;
typedef __attribute__((ext_vector_type(4))) float f32x4;

__device__ __forceinline__ float bf2f(u16 v){
  union { unsigned u; float f; } t; t.u = ((unsigned)v) << 16; return t.f;
}
__device__ __forceinline__ u16 f2bf(float f){
  union { float f; unsigned u; } t; t.f = f;
  unsigned u = t.u;
  return (u16)((u + 0x7fffu + ((u >> 16) & 1u)) >> 16);
}
struct HiLo { short hi, lo; };
__device__ __forceinline__ HiLo split1(float v){
  HiLo r;
  u16 h = f2bf(v);
  r.hi = (short)h;
  r.lo = (short)f2bf(v - bf2f(h));
  return r;
}
__device__ __forceinline__ void ldw8s(const float* __restrict__ p, short8& hi, short8& lo){
  #pragma unroll
  for (int j = 0; j < 8; ++j){ HiLo s = split1(p[j]); hi[j] = s.hi; lo[j] = s.lo; }
}

#define MFMA(acc, a, b) acc = __builtin_amdgcn_mfma_f32_16x16x32_bf16(a, b, acc, 0,0,0)
#define SMACC(acc, ah, al, bh, bl) do{ MFMA(acc, ah, bh); MFMA(acc, ah, bl); MFMA(acc, al, bh); }while(0)

// ---- pre-pass: f32 -> (hi,lo) bf16 ----------------------------------------
__global__ void wsplit(const float* __restrict__ s, u16* __restrict__ hi,
                       u16* __restrict__ lo, int n){
  int i = blockIdx.x * blockDim.x + threadIdx.x;
  if (i < n){ HiLo r = split1(s[i]); hi[i] = (u16)r.hi; lo[i] = (u16)r.lo; }
}

// ---- pre-pass: Wcomb = Wih0 @ Wout (2048x512), bb = bih0+bhh0+Wih0@bout ----
__global__ void __launch_bounds__(256) wcomb_k(
    const float* __restrict__ Wih0, const float* __restrict__ Wout,
    const float* __restrict__ bout, const float* __restrict__ bih0,
    const float* __restrict__ bhh0,
    u16* __restrict__ Wch, u16* __restrict__ Wcl, float* __restrict__ bb)
{
  __shared__ float wl[8*64];
  __shared__ float bo[64];
  const int wg = blockIdx.x, tid = threadIdx.x;
  const int r0 = wg*8;
  for (int i = tid; i < 512; i += 256) wl[i] = Wih0[(r0 + (i >> 6))*64 + (i & 63)];
  if (tid < 64) bo[tid] = bout[tid];
  __syncthreads();
  if (tid < 8){
    int n = r0 + tid;
    float a = bih0[n] + bhh0[n];
    #pragma unroll 8
    for (int d = 0; d < 64; ++d) a += wl[tid*64 + d]*bo[d];
    bb[n] = a;
  }
  #pragma unroll
  for (int jj = 0; jj < 2; ++jj){
    int j = tid + jj*256;
    float acc[8] = {0,0,0,0,0,0,0,0};
    for (int d = 0; d < 64; ++d){
      float wv = Wout[d*512 + j];
      #pragma unroll
      for (int r = 0; r < 8; ++r) acc[r] += wl[r*64 + d]*wv;
    }
    #pragma unroll
    for (int r = 0; r < 8; ++r){
      HiLo s = split1(acc[r]);
      Wch[(r0 + r)*512 + j] = (u16)s.hi;
      Wcl[(r0 + r)*512 + j] = (u16)s.lo;
    }
  }
}

// ---- grid barrier (monotone counter, agent-scope acq/rel) ------------------
__device__ __forceinline__ void gbar(unsigned* cnt, unsigned target){
  __syncthreads();
  if (threadIdx.x == 0){
    __threadfence();    // release: writeback for cross-XCD visibility
    __hip_atomic_fetch_add(cnt, 1u, __ATOMIC_RELEASE, __HIP_MEMORY_SCOPE_AGENT);
    while (__hip_atomic_load(cnt, __ATOMIC_ACQUIRE, __HIP_MEMORY_SCOPE_AGENT) < target)
      __builtin_amdgcn_s_sleep(1);
    __threadfence();    // acquire: invalidate stale caches
  }
  __syncthreads();
}

// ---- cell update (shared by persistent + fallback) -------------------------
__device__ __forceinline__ void cell_epilogue(
    float* gl, const float* bs, float* __restrict__ cbuf,
    u16* __restrict__ hhi, u16* __restrict__ hlo,
    float* __restrict__ gfout, int mrow, int jblk,
    const f32x4& a0, const f32x4& a1, int wv, int lane, int tid)
{
  __syncthreads();
  const int rbase = wv*16 + ((lane >> 4) << 2);
  const int cI = lane & 15;
  #pragma unroll
  for (int r = 0; r < 4; ++r){
    gl[(rbase+r)*33 + cI]      = a0[r] + bs[cI];
    gl[(rbase+r)*33 + 16 + cI] = a1[r] + bs[16 + cI];
  }
  __syncthreads();
  #pragma unroll
  for (int q = 0; q < 2; ++q){
    int e = tid + q*256;
    int m = e >> 3, jj = e & 7;
    float iv = gl[m*33 + jj];
    float fv = gl[m*33 + 8 + jj];
    float gv = gl[m*33 + 16 + jj];
    float ov = gl[m*33 + 24 + jj];
    float si = 1.f/(1.f + expf(-iv));
    float sf = 1.f/(1.f + expf(-fv));
    float so = 1.f/(1.f + expf(-ov));
    int gi = (mrow*64 + m)*512 + jblk*8 + jj;
    float cn = sf*cbuf[gi] + si*tanhf(gv);
    cbuf[gi] = cn;
    float h = so*tanhf(cn);
    u16 hh = f2bf(h);
    hhi[gi] = hh;
    hlo[gi] = f2bf(h - bf2f(hh));
    if (gfout) gfout[gi] = h;
  }
}

// ---- persistent kernel: 432 steps, 2 phases/step ---------------------------
__global__ void __launch_bounds__(256, 1) lstm_persist(
    const float* __restrict__ x,
    const u16* __restrict__ W0ih_h, const u16* __restrict__ W0ih_l,
    const u16* __restrict__ W0hh_h, const u16* __restrict__ W0hh_l,
    const u16* __restrict__ W1ih_h, const u16* __restrict__ W1ih_l,
    const u16* __restrict__ W1hh_h, const u16* __restrict__ W1hh_l,
    const u16* __restrict__ Wcmb_h, const u16* __restrict__ Wcmb_l,
    const float* __restrict__ bb,
    const float* __restrict__ bih0, const float* __restrict__ bhh0,
    const float* __restrict__ bih1, const float* __restrict__ bhh1,
    const float* __restrict__ Wout, const float* __restrict__ bout,
    float* __restrict__ out, unsigned* __restrict__ cnt,
    u16* __restrict__ h0h0, u16* __restrict__ h0h1,
    u16* __restrict__ h0l0, u16* __restrict__ h0l1,
    u16* __restrict__ h1h0, u16* __restrict__ h1h1,
    u16* __restrict__ h1l0, u16* __restrict__ h1l1,
    float* __restrict__ c0, float* __restrict__ c1)
{
  __shared__ float gl[64*33];
  __shared__ float bs0[32], bs1[32], bsd[32];
  __shared__ float pr[64][5];

  const int wg = blockIdx.x, tid = threadIdx.x;
  const int mrow = wg & 3, jblk = wg >> 2;
  const int lane = tid & 63, wv = tid >> 6;

  if (tid < 32){                    // bias LDS, loaded once
    int n = ((tid >> 3) << 9) + jblk*8 + (tid & 7);
    bs0[tid] = bih0[n] + bhh0[n];
    bs1[tid] = bih1[n] + bhh1[n];
    bsd[tid] = bb[n];
  }
  const float boutj = bout[jblk];

  const int ar = mrow*64 + wv*16 + (lane & 15);
  const int kc = (lane >> 4) << 3;
  const int cI = lane & 15;
  const int n0 = ((cI >> 3) << 9) + jblk*8 + (cI & 7);
  const int n1 = n0 + 1024;
  const int aoff = ar*512 + kc;

  u16* H0h[2] = { h0h0, h0h1 };  u16* H0l[2] = { h0l0, h0l1 };
  u16* H1h[2] = { h1h0, h1h1 };  u16* H1l[2] = { h1l0, h1l1 };

  const int o0 = n0*512 + kc, o1 = n1*512 + kc;   // K=512 weight frag offsets
  const float* xbase = x + ar*21504;

  unsigned ep = 0;
  __syncthreads();                  // bias LDS ready

  for (int t = 0; t < 432; ++t){
    const int p = t & 1;
    const bool enc = (t < 336);

    // =============== phase A: layer 0 ===============
    f32x4 acc0 = {0,0,0,0}, acc1 = {0,0,0,0};
    if (enc){
      #pragma unroll
      for (int ks = 0; ks < 2; ++ks){             // x seg (K=64)
        int k = ks*32 + kc;
        short8 ah, al;
        const float* xb = xbase + t;
        #pragma unroll
        for (int j = 0; j < 8; ++j){ HiLo s = split1(xb[(k + j)*336]); ah[j] = s.hi; al[j] = s.lo; }
        short8 bh0 = *(const short8*)(W0ih_h + n0*64 + k);
        short8 bl0 = *(const short8*)(W0ih_l + n0*64 + k);
        short8 bh1 = *(const short8*)(W0ih_h + n1*64 + k);
        short8 bl1 = *(const short8*)(W0ih_l + n1*64 + k);
        SMACC(acc0, ah, al, bh0, bl0);
        SMACC(acc1, ah, al, bh1, bl1);
      }
    } else if (t > 336){                          // Wcomb seg over h1_{t-1} (K=512)
      const u16* hH = H1h[p^1] + aoff;
      const u16* hL = H1l[p^1] + aoff;
      #pragma unroll 4
      for (int ks = 0; ks < 16; ++ks){
        int k = ks*32;
        short8 ah = *(const short8*)(hH + k);
        short8 al = *(const short8*)(hL + k);
        short8 bh0 = *(const short8*)(Wcmb_h + o0 + k);
        short8 bl0 = *(const short8*)(Wcmb_l + o0 + k);
        short8 bh1 = *(const short8*)(Wcmb_h + o1 + k);
        short8 bl1 = *(const short8*)(Wcmb_l + o1 + k);
        SMACC(acc0, ah, al, bh0, bl0);
        SMACC(acc1, ah, al, bh1, bl1);
      }
    }
    {                                             // Whh0 seg over h0_{t-1}
      const u16* hH = H0h[p^1] + aoff;
      const u16* hL = H0l[p^1] + aoff;
      #pragma unroll 4
      for (int ks = 0; ks < 16; ++ks){
        int k = ks*32;
        short8 ah = *(const short8*)(hH + k);
        short8 al = *(const short8*)(hL + k);
        short8 bh0 = *(const short8*)(W0hh_h + o0 + k);
        short8 bl0 = *(const short8*)(W0hh_l + o0 + k);
        short8 bh1 = *(const short8*)(W0hh_h + o1 + k);
        short8 bl1 = *(const short8*)(W0hh_l + o1 + k);
        SMACC(acc0, ah, al, bh0, bl0);
        SMACC(acc1, ah, al, bh1, bl1);
      }
    }
    // decoder pred output for l = t-337 (reads h1_{t-1}, off critical math)
    if (!enc && t > 336){
      const int bloc = tid & 63, q = tid >> 6;
      const u16* hH = H1h[p^1] + (mrow*64 + bloc)*512 + q*128;
      const u16* hL = H1l[p^1] + (mrow*64 + bloc)*512 + q*128;
      const float* wr = Wout + jblk*512 + q*128;
      float part = 0.f;
      #pragma unroll 4
      for (int k = 0; k < 128; k += 8){
        short8 hv = *(const short8*)(hH + k);
        short8 lv = *(const short8*)(hL + k);
        #pragma unroll
        for (int j = 0; j < 8; ++j)
          part += (bf2f((u16)hv[j]) + bf2f((u16)lv[j])) * wr[k + j];
      }
      pr[bloc][q] = part;
      __syncthreads();
      if (tid < 64){
        float v = pr[tid][0] + pr[tid][1] + pr[tid][2] + pr[tid][3] + boutj;
        out[131072 + ((mrow*64 + tid)*64 + jblk)*96 + (t - 337)] = v;
      }
    }
    cell_epilogue(gl, (enc || t == 336) ? bs0 : bsd, c0,
                  H0h[p], H0l[p], nullptr, mrow, jblk, acc0, acc1, wv, lane, tid);
    ++ep; gbar(cnt, ep*256u);

    // =============== phase B: layer 1 ===============
    acc0 = (f32x4){0,0,0,0}; acc1 = (f32x4){0,0,0,0};
    {
      const u16* hH = H0h[p] + aoff;              // h0_t
      const u16* hL = H0l[p] + aoff;
      #pragma unroll 4
      for (int ks = 0; ks < 16; ++ks){
        int k = ks*32;
        short8 ah = *(const short8*)(hH + k);
        short8 al = *(const short8*)(hL + k);
        short8 bh0 = *(const short8*)(W1ih_h + o0 + k);
        short8 bl0 = *(const short8*)(W1ih_l + o0 + k);
        short8 bh1 = *(const short8*)(W1ih_h + o1 + k);
        short8 bl1 = *(const short8*)(W1ih_l + o1 + k);
        SMACC(acc0, ah, al, bh0, bl0);
        SMACC(acc1, ah, al, bh1, bl1);
      }
    }
    {
      const u16* hH = H1h[p^1] + aoff;            // h1_{t-1}
      const u16* hL = H1l[p^1] + aoff;
      #pragma unroll 4
      for (int ks = 0; ks < 16; ++ks){
        int k = ks*32;
        short8 ah = *(const short8*)(hH + k);
        short8 al = *(const short8*)(hL + k);
        short8 bh0 = *(const short8*)(W1hh_h + o0 + k);
        short8 bl0 = *(const short8*)(W1hh_l + o0 + k);
        short8 bh1 = *(const short8*)(W1hh_h + o1 + k);
        short8 bl1 = *(const short8*)(W1hh_l + o1 + k);
        SMACC(acc0, ah, al, bh0, bl0);
        SMACC(acc1, ah, al, bh1, bl1);
      }
    }
    cell_epilogue(gl, bs1, c1, H1h[p], H1l[p],
                  (t == 335) ? out : (float*)nullptr,
                  mrow, jblk, acc0, acc1, wv, lane, tid);
    ++ep; gbar(cnt, ep*256u);
  }
}

// ---- tail: pred for l=95 from h1_431 ---------------------------------------
__global__ void __launch_bounds__(256) pred_last(
    const u16* __restrict__ h1hi, const u16* __restrict__ h1lo,
    const float* __restrict__ Wout, const float* __restrict__ bout,
    float* __restrict__ out)
{
  const int wg = blockIdx.x, tid = threadIdx.x;
  const int bsub = tid >> 6, d = tid & 63;
  const int b = wg*4 + bsub;
  float acc = bout[d];
  const u16* hH = h1hi + b*512;
  const u16* hL = h1lo + b*512;
  const float* wr = Wout + d*512;
  #pragma unroll 8
  for (int k = 0; k < 512; k += 8){
    short8 hv = *(const short8*)(hH + k);
    short8 lv = *(const short8*)(hL + k);
    #pragma unroll
    for (int j = 0; j < 8; ++j)
      acc += (bf2f((u16)hv[j]) + bf2f((u16)lv[j])) * wr[k + j];
  }
  out[131072 + (b*64 + d)*96 + 95] = acc;
}

// ======================= fallback (R9 proven path) ==========================
template<bool ENC>
__global__ void __launch_bounds__(256) l0_fb(
    const float* __restrict__ x,
    const u16* __restrict__ predhi, const u16* __restrict__ predlo,
    const float* __restrict__ Wihf, const float* __restrict__ Whhf,
    const float* __restrict__ bih, const float* __restrict__ bhh,
    const u16* __restrict__ hphi, const u16* __restrict__ hplo,
    u16* __restrict__ hnhi, u16* __restrict__ hnlo,
    float* __restrict__ c0, int t)
{
  __shared__ float gl[64*33];
  __shared__ float bs[32];
  const int wg = blockIdx.x, tid = threadIdx.x;
  const int mrow = wg & 3, jblk = wg >> 2;
  const int lane = tid & 63, wv = tid >> 6;
  if (tid < 32){
    int n = ((tid >> 3) << 9) + jblk*8 + (tid & 7);
    bs[tid] = bih[n] + bhh[n];
  }
  const int ar = mrow*64 + wv*16 + (lane & 15);
  const int kc = (lane >> 4) << 3;
  const int cI = lane & 15;
  const int n0 = ((cI >> 3) << 9) + jblk*8 + (cI & 7);
  const int n1 = n0 + 1024;

  f32x4 acc0 = {0,0,0,0}, acc1 = {0,0,0,0};
  #pragma unroll
  for (int ks = 0; ks < 2; ++ks){
    int k = ks*32 + kc;
    short8 ah, al;
    if (ENC){
      const float* xb = x + ar*21504 + t;
      #pragma unroll
      for (int j = 0; j < 8; ++j){ HiLo s = split1(xb[(k + j)*336]); ah[j] = s.hi; al[j] = s.lo; }
    } else {
      ah = *(const short8*)(predhi + ar*64 + k);
      al = *(const short8*)(predlo + ar*64 + k);
    }
    short8 bh0, bl0, bh1, bl1;
    ldw8s(Wihf + n0*64 + k, bh0, bl0);
    ldw8s(Wihf + n1*64 + k, bh1, bl1);
    SMACC(acc0, ah, al, bh0, bl0);
    SMACC(acc1, ah, al, bh1, bl1);
  }
  const u16* hH = hphi + ar*512 + kc;
  const u16* hL = hplo + ar*512 + kc;
  #pragma unroll 4
  for (int ks = 0; ks < 16; ++ks){
    int k = ks*32;
    short8 ah = *(const short8*)(hH + k);
    short8 al = *(const short8*)(hL + k);
    short8 bh0, bl0, bh1, bl1;
    ldw8s(Whhf + n0*512 + kc + k, bh0, bl0);
    ldw8s(Whhf + n1*512 + kc + k, bh1, bl1);
    SMACC(acc0, ah, al, bh0, bl0);
    SMACC(acc1, ah, al, bh1, bl1);
  }
  cell_epilogue(gl, bs, c0, hnhi, hnlo, nullptr, mrow, jblk, acc0, acc1, wv, lane, tid);
}

__global__ void __launch_bounds__(256) l1_fb(
    const float* __restrict__ Wihf, const float* __restrict__ Whhf,
    const float* __restrict__ bih, const float* __restrict__ bhh,
    const u16* __restrict__ h0hi, const u16* __restrict__ h0lo,
    const u16* __restrict__ h1phi, const u16* __restrict__ h1plo,
    u16* __restrict__ h1nhi, u16* __restrict__ h1nlo,
    float* __restrict__ c1, float* __restrict__ gfout)
{
  __shared__ float gl[64*33];
  __shared__ float bs[32];
  const int wg = blockIdx.x, tid = threadIdx.x;
  const int mrow = wg & 3, jblk = wg >> 2;
  const int lane = tid & 63, wv = tid >> 6;
  if (tid < 32){
    int n = ((tid >> 3) << 9) + jblk*8 + (tid & 7);
    bs[tid] = bih[n] + bhh[n];
  }
  const int ar = mrow*64 + wv*16 + (lane & 15);
  const int kc = (lane >> 4) << 3;
  const int cI = lane & 15;
  const int n0 = ((cI >> 3) << 9) + jblk*8 + (cI & 7);
  const int n1 = n0 + 1024;

  f32x4 acc0 = {0,0,0,0}, acc1 = {0,0,0,0};
  {
    const u16* hH = h0hi + ar*512 + kc;
    const u16* hL = h0lo + ar*512 + kc;
    #pragma unroll 4
    for (int ks = 0; ks < 16; ++ks){
      int k = ks*32;
      short8 ah = *(const short8*)(hH + k);
      short8 al = *(const short8*)(hL + k);
      short8 bh0, bl0, bh1, bl1;
      ldw8s(Wihf + n0*512 + kc + k, bh0, bl0);
      ldw8s(Wihf + n1*512 + kc + k, bh1, bl1);
      SMACC(acc0, ah, al, bh0, bl0);
      SMACC(acc1, ah, al, bh1, bl1);
    }
  }
  {
    const u16* hH = h1phi + ar*512 + kc;
    const u16* hL = h1plo + ar*512 + kc;
    #pragma unroll 4
    for (int ks = 0; ks < 16; ++ks){
      int k = ks*32;
      short8 ah = *(const short8*)(hH + k);
      short8 al = *(const short8*)(hL + k);
      short8 bh0, bl0, bh1, bl1;
      ldw8s(Whhf + n0*512 + kc + k, bh0, bl0);
      ldw8s(Whhf + n1*512 + kc + k, bh1, bl1);
      SMACC(acc0, ah, al, bh0, bl0);
      SMACC(acc1, ah, al, bh1, bl1);
    }
  }
  cell_epilogue(gl, bs, c1, h1nhi, h1nlo, gfout, mrow, jblk, acc0, acc1, wv, lane, tid);
}

__global__ void __launch_bounds__(256) pred_fb(
    const u16* __restrict__ h1hi, const u16* __restrict__ h1lo,
    const float* __restrict__ Wout, const float* __restrict__ bout,
    u16* __restrict__ predhi, u16* __restrict__ predlo,
    float* __restrict__ out, int l)
{
  const int wg = blockIdx.x, tid = threadIdx.x;
  const int bsub = tid >> 6, d = tid & 63;
  const int b = wg*4 + bsub;
  float acc = bout[d];
  const u16* hH = h1hi + b*512;
  const u16* hL = h1lo + b*512;
  const float* wr = Wout + d*512;
  #pragma unroll 8
  for (int k = 0; k < 512; k += 8){
    short8 hv = *(const short8*)(hH + k);
    short8 lv = *(const short8*)(hL + k);
    #pragma unroll
    for (int j = 0; j < 8; ++j)
      acc += (bf2f((u16)hv[j]) + bf2f((u16)lv[j])) * wr[k + j];
  }
  HiLo s = split1(acc);
  predhi[b*64 + d] = (u16)s.hi;
  predlo[b*64 + d] = (u16)s.lo;
  out[131072 + (b*64 + d)*96 + l] = acc;
}

extern "C" void kernel_launch(void* const* d_in, const int* in_sizes, int n_in,
                              void* d_out, int out_size, void* d_ws, size_t ws_size,
                              hipStream_t stream)
{
  const float* x    = (const float*)d_in[0];
  const float* Wih0 = (const float*)d_in[1];
  const float* Whh0 = (const float*)d_in[2];
  const float* bih0 = (const float*)d_in[3];
  const float* bhh0 = (const float*)d_in[4];
  const float* Wih1 = (const float*)d_in[5];
  const float* Whh1 = (const float*)d_in[6];
  const float* bih1 = (const float*)d_in[7];
  const float* bhh1 = (const float*)d_in[8];
  const float* Wout = (const float*)d_in[9];
  const float* bout = (const float*)d_in[10];
  float* out = (float*)d_out;

  // ---- ws layout
  char* ws = (char*)d_ws;
  u16* h0h[2] = { (u16*)(ws + 0),       (u16*)(ws + 262144) };
  u16* h0l[2] = { (u16*)(ws + 524288),  (u16*)(ws + 786432) };
  u16* h1h[2] = { (u16*)(ws + 1048576), (u16*)(ws + 1310720) };
  u16* h1l[2] = { (u16*)(ws + 1572864), (u16*)(ws + 1835008) };
  float* c0   = (float*)(ws + 2097152);
  float* c1   = (float*)(ws + 2621440);
  unsigned* cnt = (unsigned*)(ws + 3145728);      // main path
  u16* predh  = (u16*)(ws + 3145728);             // fallback path
  u16* predl  = (u16*)(ws + 3178496);
  char* wb = ws + 3149824;                        // pre-split weights (main)
  u16* W0ih_h = (u16*)wb;                u16* W0ih_l = W0ih_h + 131072;
  u16* W0hh_h = W0ih_l + 131072;         u16* W0hh_l = W0hh_h + 1048576;
  u16* W1ih_h = W0hh_l + 1048576;        u16* W1ih_l = W1ih_h + 1048576;
  u16* W1hh_h = W1ih_l + 1048576;        u16* W1hh_l = W1hh_h + 1048576;
  u16* Wcmb_h = W1hh_l + 1048576;        u16* Wcmb_l = Wcmb_h + 1048576;
  float* bb   = (float*)(Wcmb_l + 1048576);
  const size_t NEED = 3149824u + 2u*(2*131072u + 8*1048576u) + 8192u;
  const bool ps = (ws_size >= NEED);

  (void)hipMemsetAsync(d_ws, 0, 3211264, stream);   // state (+cnt / predbf)

  if (ps){
    wsplit<<<dim3(512),  dim3(256), 0, stream>>>(Wih0, W0ih_h, W0ih_l, 131072);
    wsplit<<<dim3(4096), dim3(256), 0, stream>>>(Whh0, W0hh_h, W0hh_l, 1048576);
    wsplit<<<dim3(4096), dim3(256), 0, stream>>>(Wih1, W1ih_h, W1ih_l, 1048576);
    wsplit<<<dim3(4096), dim3(256), 0, stream>>>(Whh1, W1hh_h, W1hh_l, 1048576);
    wcomb_k<<<dim3(256), dim3(256), 0, stream>>>(Wih0, Wout, bout, bih0, bhh0,
                                                 Wcmb_h, Wcmb_l, bb);
    lstm_persist<<<dim3(256), dim3(256), 0, stream>>>(
        x, W0ih_h, W0ih_l, W0hh_h, W0hh_l, W1ih_h, W1ih_l, W1hh_h, W1hh_l,
        Wcmb_h, Wcmb_l, bb, bih0, bhh0, bih1, bhh1, Wout, bout,
        out, cnt,
        h0h[0], h0h[1], h0l[0], h0l[1], h1h[0], h1h[1], h1l[0], h1l[1],
        c0, c1);
    pred_last<<<dim3(64), dim3(256), 0, stream>>>(h1h[1], h1l[1], Wout, bout, out);
  } else {
    for (int t = 0; t < 432; ++t){
      const int p = t & 1;
      float* gf = (t == 335) ? out : (float*)nullptr;
      if (t < 336)
        l0_fb<true><<<dim3(256), dim3(256), 0, stream>>>(
            x, predh, predl, Wih0, Whh0, bih0, bhh0,
            h0h[p^1], h0l[p^1], h0h[p], h0l[p], c0, t);
      else
        l0_fb<false><<<dim3(256), dim3(256), 0, stream>>>(
            x, predh, predl, Wih0, Whh0, bih0, bhh0,
            h0h[p^1], h0l[p^1], h0h[p], h0l[p], c0, t);
      l1_fb<<<dim3(256), dim3(256), 0, stream>>>(
          Wih1, Whh1, bih1, bhh1, h0h[p], h0l[p],
          h1h[p^1], h1l[p^1], h1h[p], h1l[p], c1, gf);
      if (t >= 336)
        pred_fb<<<dim3(64), dim3(256), 0, stream>>>(
            h1h[p], h1l[p], Wout, bout, predh, predl, out, t - 336);
    }
  }
}